// Round 1
// baseline (821.925 us; speedup 1.0000x reference)
//
#include <hip/hip_runtime.h>
#include <hip/hip_fp16.h>

#define C_   256
#define H_   224
#define W_   224
#define NWH  28
#define NWW  28
#define NWIN 3136

typedef _Float16 f16x8 __attribute__((ext_vector_type(8)));
typedef float    f32x4 __attribute__((ext_vector_type(4)));

// ---------------- weight fp32 -> fp16 conversion (runs every launch) --------
__global__ void wcvt_kernel(const float* __restrict__ wqkv,
                            const float* __restrict__ wout,
                            _Float16* __restrict__ dst) {
  const int total = 768 * 256 + 256 * 256;
  for (int i = blockIdx.x * blockDim.x + threadIdx.x; i < total;
       i += gridDim.x * blockDim.x) {
    float v = (i < 768 * 256) ? wqkv[i] : wout[i - 768 * 256];
    dst[i] = (_Float16)v;
  }
}

template <bool USE_WS>
__device__ __forceinline__ f16x8 load_bfrag(const _Float16* __restrict__ w16,
                                            const float* __restrict__ w32,
                                            int idx) {
  if constexpr (USE_WS) {
    return *(const f16x8*)(w16 + idx);
  } else {
    f32x4 a = *(const f32x4*)(w32 + idx);
    f32x4 b = *(const f32x4*)(w32 + idx + 4);
    f16x8 r;
#pragma unroll
    for (int q = 0; q < 4; ++q) { r[q] = (_Float16)a[q]; r[q + 4] = (_Float16)b[q]; }
    return r;
  }
}

// ---------------- fused window attention ------------------------------------
// one block = one 8x8 window (64 tokens, C=256). 256 threads = 4 waves.
// LDS map (bytes):
//   [0      , 36864) : union { xn fp16 [64][264] | p fp16 [4][64][72] | o fp16 [64][264] }
//   [36864  , 70656) : q fp16 [64][264]   (scaled by 1/sqrt(32), bias added)
//   [70656  ,104448) : k fp16 [64][264]
//   [104448 ,137216) : v fp16 [64][256]
//   [137216 ,139264) : LN partial sum/sumsq  f32 [2][4][64]
//   [139264 ,139776) : mean / rstd           f32 [2][64]
template <bool USE_WS>
__global__ __launch_bounds__(256, 1) void winattn_kernel(
    const float* __restrict__ x, const float* __restrict__ gamma,
    const float* __restrict__ beta, const float* __restrict__ wqkv32,
    const float* __restrict__ bqkv, const float* __restrict__ wout32,
    const float* __restrict__ bout, const _Float16* __restrict__ w16,
    float* __restrict__ out) {
  extern __shared__ char smem[];
  _Float16* xsh = (_Float16*)smem;             // [64][264]
  _Float16* qs  = (_Float16*)(smem + 36864);   // [64][264]
  _Float16* ksd = (_Float16*)(smem + 70656);   // [64][264]
  _Float16* vs  = (_Float16*)(smem + 104448);  // [64][256]
  float* red = (float*)(smem + 137216);        // [2][4][64]
  float* mrs = red + 512;                      // [2][64]

  const int n  = blockIdx.x;
  const int b  = n / (NWH * NWW);
  const int wh = (n / NWW) % NWH;
  const int ww = n % NWW;
  const int tid  = threadIdx.x;
  const int w    = tid >> 6;
  const int lane = tid & 63;
  const int lr   = lane & 15;  // row/col within a 16-tile
  const int lg   = lane >> 4;  // 0..3 lane group

  // ---- phase 1: load window (raw fp16 into LDS) + LN partial sums ----
  const int c0 = w * 64;  // wave's channel range
  {
    const float* xp = x + (size_t)b * C_ * H_ * W_ + (size_t)c0 * H_ * W_ +
                      (size_t)(wh * 8 + (lane >> 3)) * W_ + ww * 8 + (lane & 7);
    float sum = 0.f, sq = 0.f;
#pragma unroll
    for (int j = 0; j < 8; ++j) {
      f16x8 pk;
#pragma unroll
      for (int jj = 0; jj < 8; ++jj) {
        float v = xp[(size_t)(j * 8 + jj) * (H_ * W_)];
        sum += v;
        sq += v * v;
        pk[jj] = (_Float16)v;
      }
      *(f16x8*)&xsh[lane * 264 + c0 + j * 8] = pk;
    }
    red[w * 64 + lane] = sum;
    red[256 + w * 64 + lane] = sq;
  }
  __syncthreads();

  // ---- phase 2: LN stats (token t = tid) ----
  if (tid < 64) {
    float s  = red[tid] + red[64 + tid] + red[128 + tid] + red[192 + tid];
    float s2 = red[256 + tid] + red[320 + tid] + red[384 + tid] + red[448 + tid];
    float mu  = s * (1.f / 256.f);
    float var = s2 * (1.f / 256.f) - mu * mu;
    mrs[tid]      = mu;
    mrs[64 + tid] = rsqrtf(var + 1e-5f);
  }
  __syncthreads();

  // ---- phase 3: normalize in place ----
  {
    const float mu = mrs[lane], rs = mrs[64 + lane];
#pragma unroll
    for (int j = 0; j < 8; ++j) {
      f16x8 hv = *(f16x8*)&xsh[lane * 264 + c0 + j * 8];
      const float* gp = gamma + c0 + j * 8;
      const float* bp = beta + c0 + j * 8;
#pragma unroll
      for (int jj = 0; jj < 8; ++jj) {
        float f = (float)hv[jj];
        hv[jj] = (_Float16)((f - mu) * rs * gp[jj] + bp[jj]);
      }
      *(f16x8*)&xsh[lane * 264 + c0 + j * 8] = hv;
    }
  }
  __syncthreads();

  // ---- phase 4: QKV projection, M=64 K=256, wave w owns N cols [192w,192w+192) ----
  {
    f16x8 afr[4][8];
#pragma unroll
    for (int mi = 0; mi < 4; ++mi)
#pragma unroll
      for (int kk = 0; kk < 8; ++kk)
        afr[mi][kk] = *(f16x8*)&xsh[(mi * 16 + lr) * 264 + kk * 32 + lg * 8];

    const float sc_q = 0.17677669529663687f;  // 1/sqrt(32)
#pragma unroll 1
    for (int ntl = 0; ntl < 12; ++ntl) {
      const int ncol = w * 192 + ntl * 16;  // global output column base (0..767)
      f32x4 acc[4];
#pragma unroll
      for (int mi = 0; mi < 4; ++mi) acc[mi] = (f32x4){0.f, 0.f, 0.f, 0.f};
      const int wb = (ncol + lr) * 256 + lg * 8;
#pragma unroll
      for (int kk = 0; kk < 8; ++kk) {
        f16x8 bf = load_bfrag<USE_WS>(w16, wqkv32, wb + kk * 32);
#pragma unroll
        for (int mi = 0; mi < 4; ++mi)
          acc[mi] = __builtin_amdgcn_mfma_f32_16x16x32_f16(afr[mi][kk], bf,
                                                           acc[mi], 0, 0, 0);
      }
      const float bias = bqkv[ncol + lr];
      const int sect = ncol >> 8;   // 0=q 1=k 2=v (uniform per iteration)
      const int cloc = ncol & 255;
#pragma unroll
      for (int mi = 0; mi < 4; ++mi)
#pragma unroll
        for (int i = 0; i < 4; ++i) {
          const int trow = mi * 16 + lg * 4 + i;
          const float v = acc[mi][i] + bias;
          if (sect == 0)
            qs[trow * 264 + cloc + lr] = (_Float16)(v * sc_q);
          else if (sect == 1)
            ksd[trow * 264 + cloc + lr] = (_Float16)v;
          else
            vs[trow * 256 + cloc + lr] = (_Float16)v;
        }
    }
  }
  __syncthreads();

  // ---- phase 5: attention, wave w owns heads 2w, 2w+1 ----
  f32x4 oacc[2][4][2];
  f32x4 oinv[2][4];
  {
    _Float16* pbuf = (_Float16*)(smem + w * 9216);  // per-wave [64][72]
#pragma unroll 1
    for (int hl = 0; hl < 2; ++hl) {
      const int hc = (w * 2 + hl) * 32;
      f16x8 qa[4], kb[4];
#pragma unroll
      for (int mi = 0; mi < 4; ++mi)
        qa[mi] = *(f16x8*)&qs[(mi * 16 + lr) * 264 + hc + lg * 8];
#pragma unroll
      for (int ni = 0; ni < 4; ++ni)
        kb[ni] = *(f16x8*)&ksd[(ni * 16 + lr) * 264 + hc + lg * 8];
      f32x4 sc[4][4];
#pragma unroll
      for (int mi = 0; mi < 4; ++mi)
#pragma unroll
        for (int ni = 0; ni < 4; ++ni) {
          f32x4 z = {0.f, 0.f, 0.f, 0.f};
          sc[mi][ni] = __builtin_amdgcn_mfma_f32_16x16x32_f16(qa[mi], kb[ni], z, 0, 0, 0);
        }
      // softmax over k (row r = mi*16 + lg*4 + i lives in the 16 lanes of group lg)
#pragma unroll
      for (int mi = 0; mi < 4; ++mi)
#pragma unroll
        for (int i = 0; i < 4; ++i) {
          float m = fmaxf(fmaxf(sc[mi][0][i], sc[mi][1][i]),
                          fmaxf(sc[mi][2][i], sc[mi][3][i]));
          m = fmaxf(m, __shfl_xor(m, 1));
          m = fmaxf(m, __shfl_xor(m, 2));
          m = fmaxf(m, __shfl_xor(m, 4));
          m = fmaxf(m, __shfl_xor(m, 8));
          float s = 0.f;
#pragma unroll
          for (int ni = 0; ni < 4; ++ni) {
            float e = __expf(sc[mi][ni][i] - m);
            sc[mi][ni][i] = e;
            s += e;
          }
          s += __shfl_xor(s, 1);
          s += __shfl_xor(s, 2);
          s += __shfl_xor(s, 4);
          s += __shfl_xor(s, 8);
          oinv[hl][mi][i] = 1.f / s;
        }
      // p (unnormalized) -> per-wave LDS
#pragma unroll
      for (int mi = 0; mi < 4; ++mi)
#pragma unroll
        for (int ni = 0; ni < 4; ++ni)
#pragma unroll
          for (int i = 0; i < 4; ++i)
            pbuf[(mi * 16 + lg * 4 + i) * 72 + ni * 16 + lr] = (_Float16)sc[mi][ni][i];
      // PV: o = p(64x64) @ v(64x32)
#pragma unroll
      for (int mi = 0; mi < 4; ++mi)
#pragma unroll
        for (int nt2 = 0; nt2 < 2; ++nt2)
          oacc[hl][mi][nt2] = (f32x4){0.f, 0.f, 0.f, 0.f};
#pragma unroll
      for (int ks2 = 0; ks2 < 2; ++ks2) {
        f16x8 pa[4];
#pragma unroll
        for (int mi = 0; mi < 4; ++mi)
          pa[mi] = *(f16x8*)&pbuf[(mi * 16 + lr) * 72 + ks2 * 32 + lg * 8];
#pragma unroll
        for (int nt2 = 0; nt2 < 2; ++nt2) {
          f16x8 vb;
#pragma unroll
          for (int j = 0; j < 8; ++j)
            vb[j] = vs[(ks2 * 32 + lg * 8 + j) * 256 + hc + nt2 * 16 + lr];
#pragma unroll
          for (int mi = 0; mi < 4; ++mi)
            oacc[hl][mi][nt2] = __builtin_amdgcn_mfma_f32_16x16x32_f16(
                pa[mi], vb, oacc[hl][mi][nt2], 0, 0, 0);
        }
      }
      // normalize rows (same lane->row map as scores)
#pragma unroll
      for (int mi = 0; mi < 4; ++mi)
#pragma unroll
        for (int nt2 = 0; nt2 < 2; ++nt2)
#pragma unroll
          for (int i = 0; i < 4; ++i)
            oacc[hl][mi][nt2][i] *= oinv[hl][mi][i];
    }
  }
  __syncthreads();  // all waves done with p buffers

  // ---- phase 6: merged-head o -> LDS (overlays p/xn region) ----
  {
    _Float16* osh = (_Float16*)smem;  // [64][264]
#pragma unroll
    for (int hl = 0; hl < 2; ++hl) {
      const int hc = (w * 2 + hl) * 32;
#pragma unroll
      for (int mi = 0; mi < 4; ++mi)
#pragma unroll
        for (int nt2 = 0; nt2 < 2; ++nt2)
#pragma unroll
          for (int i = 0; i < 4; ++i)
            osh[(mi * 16 + lg * 4 + i) * 264 + hc + nt2 * 16 + lr] =
                (_Float16)oacc[hl][mi][nt2][i];
    }
  }
  __syncthreads();

  // ---- phase 7: out projection + window reverse, wave w owns cols [64w,64w+64) ----
  {
    const _Float16* osh = (const _Float16*)smem;
    f16x8 ofr[4][8];
#pragma unroll
    for (int mi = 0; mi < 4; ++mi)
#pragma unroll
      for (int kk = 0; kk < 8; ++kk)
        ofr[mi][kk] = *(const f16x8*)&osh[(mi * 16 + lr) * 264 + kk * 32 + lg * 8];
    const _Float16* w16o = USE_WS ? (w16 + 768 * 256) : (const _Float16*)nullptr;
#pragma unroll 1
    for (int ntl = 0; ntl < 4; ++ntl) {
      const int ncol = w * 64 + ntl * 16;
      f32x4 acc[4];
#pragma unroll
      for (int mi = 0; mi < 4; ++mi) acc[mi] = (f32x4){0.f, 0.f, 0.f, 0.f};
      const int wb = (ncol + lr) * 256 + lg * 8;
#pragma unroll
      for (int kk = 0; kk < 8; ++kk) {
        f16x8 bf = load_bfrag<USE_WS>(w16o, wout32, wb + kk * 32);
#pragma unroll
        for (int mi = 0; mi < 4; ++mi)
          acc[mi] = __builtin_amdgcn_mfma_f32_16x16x32_f16(ofr[mi][kk], bf,
                                                           acc[mi], 0, 0, 0);
      }
      const int och = ncol + lr;
      const float bias = bout[och];
      float* ob = out + ((size_t)(b * C_ + och) * H_ + wh * 8) * W_ + ww * 8;
#pragma unroll
      for (int mi = 0; mi < 4; ++mi) {
        const int tb = mi * 16 + lg * 4;  // 4 consecutive tokens, same window row
        f32x4 ov;
#pragma unroll
        for (int i = 0; i < 4; ++i) ov[i] = acc[mi][i] + bias;
        *(f32x4*)&ob[(size_t)(tb >> 3) * W_ + (tb & 7)] = ov;
      }
    }
  }
}

extern "C" void kernel_launch(void* const* d_in, const int* in_sizes, int n_in,
                              void* d_out, int out_size, void* d_ws, size_t ws_size,
                              hipStream_t stream) {
  (void)in_sizes; (void)n_in; (void)out_size;
  const float* x     = (const float*)d_in[0];
  const float* gamma = (const float*)d_in[1];
  const float* beta  = (const float*)d_in[2];
  const float* wqkv  = (const float*)d_in[3];
  const float* bqkv  = (const float*)d_in[4];
  const float* wout  = (const float*)d_in[5];
  const float* bout  = (const float*)d_in[6];
  float* out = (float*)d_out;

  const size_t need_ws = (size_t)(768 * 256 + 256 * 256) * sizeof(_Float16);
  const int shmem = 139776;

  if (ws_size >= need_ws) {
    _Float16* w16 = (_Float16*)d_ws;
    wcvt_kernel<<<256, 256, 0, stream>>>(wqkv, wout, w16);
    static int attr_set = 0;  // idempotent host-side attribute (not a stream op)
    if (!attr_set) {
      (void)hipFuncSetAttribute((const void*)winattn_kernel<true>,
                                hipFuncAttributeMaxDynamicSharedMemorySize, shmem);
      attr_set = 1;
    }
    winattn_kernel<true><<<NWIN, 256, shmem, stream>>>(
        x, gamma, beta, wqkv, bqkv, wout, bout, w16, out);
  } else {
    static int attr_set2 = 0;
    if (!attr_set2) {
      (void)hipFuncSetAttribute((const void*)winattn_kernel<false>,
                                hipFuncAttributeMaxDynamicSharedMemorySize, shmem);
      attr_set2 = 1;
    }
    winattn_kernel<false><<<NWIN, 256, shmem, stream>>>(
        x, gamma, beta, wqkv, bqkv, wout, bout, (const _Float16*)nullptr, out);
  }
}

// Round 3
// 635.387 us; speedup vs baseline: 1.2936x; 1.2936x over previous
//
#include <hip/hip_runtime.h>
#include <hip/hip_fp16.h>

#define C_   256
#define H_   224
#define W_   224
#define HW_  (224 * 224)
#define NWH  28
#define NWW  28
#define NWIN 3136
#define NTILE 64  // 48 qkv tiles + 16 out-proj tiles
#define NFRAG (NTILE * 8 * 64)

typedef _Float16 f16x8 __attribute__((ext_vector_type(8)));
typedef float    f32x4 __attribute__((ext_vector_type(4)));

// ---- weight fp32 -> fragment-major fp16 (B-frag for mfma_f32_16x16x32_f16) --
// frag f = (tile*8 + kk)*64 + lane ; value j = W[tile*16 + (lane&15)][kk*32 + (lane>>4)*8 + j]
__global__ void wcvt_kernel(const float* __restrict__ wqkv,
                            const float* __restrict__ wout,
                            _Float16* __restrict__ dst) {
  int f = blockIdx.x * blockDim.x + threadIdx.x;
  if (f >= NFRAG) return;
  int lane = f & 63, kk = (f >> 6) & 7, tile = f >> 9;
  int row = tile * 16 + (lane & 15);
  int col = kk * 32 + (lane >> 4) * 8;
  const float* src = (tile < 48) ? (wqkv + row * 256 + col)
                                 : (wout + (row - 768) * 256 + col);
  f32x4 a = *(const f32x4*)src;
  f32x4 b2 = *(const f32x4*)(src + 4);
  f16x8 r;
#pragma unroll
  for (int q = 0; q < 4; ++q) { r[q] = (_Float16)a[q]; r[q + 4] = (_Float16)b2[q]; }
  *(f16x8*)(dst + (size_t)f * 8) = r;
}

// ---- swizzled LDS accessors (XOR bits live in byte[6:4]: bijective per row,
// keeps 16B alignment; gives 2-way (free) bank pattern for 16-lane groups) ----
__device__ __forceinline__ _Float16* xn_at(char* s, int row, int col) {
  return (_Float16*)(s + ((row * 512 + col * 2) ^ ((row & 7) << 4)));
}
__device__ __forceinline__ _Float16* qk_at(char* b, int row, int col) {
  return (_Float16*)(b + ((row * 64 + col * 2) ^ (((row >> 1) & 3) << 4)));
}
__device__ __forceinline__ _Float16* p_at(char* b, int row, int col) {
  return (_Float16*)(b + ((row * 128 + col * 2) ^ ((row & 7) << 4)));
}
__device__ __forceinline__ _Float16* vt_at(char* b, int d, int k) {
  return (_Float16*)(b + ((d * 128 + k * 2) ^ ((d & 7) << 4)));
}

template <bool USE_WS>
__device__ __forceinline__ f16x8 bfrag(const _Float16* __restrict__ w16,
                                       const float* __restrict__ wqkv,
                                       const float* __restrict__ wout,
                                       int gt, int kk, int lane) {
  if constexpr (USE_WS) {
    return *(const f16x8*)(w16 + ((size_t)((gt * 8 + kk) * 64 + lane)) * 8);
  } else {
    int row = gt * 16 + (lane & 15);
    int col = kk * 32 + (lane >> 4) * 8;
    const float* src = (gt < 48) ? (wqkv + row * 256 + col)
                                 : (wout + (row - 768) * 256 + col);
    f32x4 a = *(const f32x4*)src;
    f32x4 b2 = *(const f32x4*)(src + 4);
    f16x8 r;
#pragma unroll
    for (int q = 0; q < 4; ++q) { r[q] = (_Float16)a[q]; r[q + 4] = (_Float16)b2[q]; }
    return r;
  }
}

// ---- fused window attention: 1 block = 1 window, 256 thr = 4 waves ----------
// LDS (81920 B total -> 2 blocks/CU):
//   [0,32768)          xn fp16 [64 tok][256 ch], swizzled; later reused as merged-o
//   [32768, 81920)     per-wave scratch, wave w at 32768 + w*12288:
//        [0,4096) qbuf [64][32] | [4096,8192) kbuf [64][32] | [8192,12288) vT [32][64]
//        p [64][64] overlays qbuf+kbuf after scores
//   LN reduction (2.5 KB) overlays wave-0/1 scratch during phases 1-3.
template <bool USE_WS>
__global__ __launch_bounds__(256, 2) void winattn_kernel(
    const float* __restrict__ x, const float* __restrict__ gamma,
    const float* __restrict__ beta, const float* __restrict__ wqkv32,
    const float* __restrict__ bqkv, const float* __restrict__ wout32,
    const float* __restrict__ bout, const _Float16* __restrict__ w16,
    float* __restrict__ out) {
  extern __shared__ char smem[];
  float* red = (float*)(smem + 32768);  // [2][4][64] f32
  float* mrs = red + 512;               // [2][64] f32

  // XCD-aware swizzle: 3136 = 8*392; XCD x gets contiguous window range.
  const int n0 = blockIdx.x;
  const int n  = (n0 & 7) * (NWIN / 8) + (n0 >> 3);
  const int b  = n / (NWH * NWW);
  const int wh = (n / NWW) % NWH;
  const int ww = n % NWW;
  const int tid  = threadIdx.x;
  const int w    = tid >> 6;
  const int lane = tid & 63;
  const int lr   = lane & 15;
  const int lg   = lane >> 4;

  // ---- phase 1: stage x (fp16, swizzled) + LN partial sums ----
  const int c0 = w * 64;
  {
    const float* xp = x + (size_t)b * C_ * HW_ + (size_t)c0 * HW_ +
                      (size_t)(wh * 8 + (lane >> 3)) * W_ + ww * 8 + (lane & 7);
    float sum = 0.f, sq = 0.f;
#pragma unroll
    for (int j = 0; j < 8; ++j) {
      f16x8 pk;
#pragma unroll
      for (int jj = 0; jj < 8; ++jj) {
        float v = xp[(size_t)(j * 8 + jj) * HW_];
        sum += v; sq += v * v;
        pk[jj] = (_Float16)v;
      }
      *(f16x8*)xn_at(smem, lane, c0 + j * 8) = pk;
    }
    red[w * 64 + lane] = sum;
    red[256 + w * 64 + lane] = sq;
  }
  __syncthreads();

  // ---- phase 2: LN stats ----
  if (tid < 64) {
    float s  = red[tid] + red[64 + tid] + red[128 + tid] + red[192 + tid];
    float s2 = red[256 + tid] + red[320 + tid] + red[384 + tid] + red[448 + tid];
    float mu  = s * (1.f / 256.f);
    float var = s2 * (1.f / 256.f) - mu * mu;
    mrs[tid]      = mu;
    mrs[64 + tid] = rsqrtf(var + 1e-5f);
  }
  __syncthreads();

  // ---- phase 3: normalize in place ----
  {
    const float mu = mrs[lane], rs = mrs[64 + lane];
#pragma unroll
    for (int j = 0; j < 8; ++j) {
      f16x8 hv = *(f16x8*)xn_at(smem, lane, c0 + j * 8);
      f32x4 g0 = *(const f32x4*)(gamma + c0 + j * 8);
      f32x4 g1 = *(const f32x4*)(gamma + c0 + j * 8 + 4);
      f32x4 b0 = *(const f32x4*)(beta + c0 + j * 8);
      f32x4 b1 = *(const f32x4*)(beta + c0 + j * 8 + 4);
#pragma unroll
      for (int jj = 0; jj < 4; ++jj) {
        hv[jj]     = (_Float16)(((float)hv[jj] - mu) * rs * g0[jj] + b0[jj]);
        hv[jj + 4] = (_Float16)(((float)hv[jj + 4] - mu) * rs * g1[jj] + b1[jj]);
      }
      *(f16x8*)xn_at(smem, lane, c0 + j * 8) = hv;
    }
  }
  __syncthreads();

  // ---- phase 4+5: per-wave head-local QKV + attention (no barriers) ----
  char* scr   = smem + 32768 + w * 12288;
  char* kbase = scr + 4096;
  char* vbase = scr + 8192;
  f32x4 oacc[2][4][2];
  f32x4 oinv2[2][4];
  const float sc_q = 0.17677669529663687f;  // 1/sqrt(32)

#pragma unroll
  for (int hl = 0; hl < 2; ++hl) {
    const int hcol  = (2 * w + hl) * 32;
    const int tbase = w * 4 + hl * 2;
    // QKV for this head: 6 tiles share the same A-frags
    f32x4 acc[6][4];
#pragma unroll
    for (int t = 0; t < 6; ++t)
#pragma unroll
      for (int mi = 0; mi < 4; ++mi) acc[t][mi] = (f32x4){0.f, 0.f, 0.f, 0.f};
#pragma unroll
    for (int kk = 0; kk < 8; ++kk) {
      f16x8 af[4];
#pragma unroll
      for (int mi = 0; mi < 4; ++mi)
        af[mi] = *(const f16x8*)xn_at(smem, mi * 16 + lr, kk * 32 + lg * 8);
#pragma unroll
      for (int t = 0; t < 6; ++t) {
        const int gt = (t >> 1) * 16 + tbase + (t & 1);
        f16x8 bf = bfrag<USE_WS>(w16, wqkv32, wout32, gt, kk, lane);
#pragma unroll
        for (int mi = 0; mi < 4; ++mi)
          acc[t][mi] = __builtin_amdgcn_mfma_f32_16x16x32_f16(af[mi], bf, acc[t][mi], 0, 0, 0);
      }
    }
    // epilogues: q scaled+bias, k bias, v bias transposed
#pragma unroll
    for (int t2 = 0; t2 < 2; ++t2) {
      const float bq = bqkv[hcol + t2 * 16 + lr];
      const float bk = bqkv[256 + hcol + t2 * 16 + lr];
      const float bv = bqkv[512 + hcol + t2 * 16 + lr];
#pragma unroll
      for (int mi = 0; mi < 4; ++mi)
#pragma unroll
        for (int i = 0; i < 4; ++i) {
          const int trow = mi * 16 + lg * 4 + i;
          *qk_at(scr,   trow, t2 * 16 + lr) = (_Float16)((acc[t2][mi][i] + bq) * sc_q);
          *qk_at(kbase, trow, t2 * 16 + lr) = (_Float16)(acc[2 + t2][mi][i] + bk);
          *vt_at(vbase, t2 * 16 + lr, trow) = (_Float16)(acc[4 + t2][mi][i] + bv);
        }
    }
    // scores = q @ k^T (K = 32 in one MFMA)
    f16x8 qa[4], kb[4];
#pragma unroll
    for (int mi = 0; mi < 4; ++mi)
      qa[mi] = *(const f16x8*)qk_at(scr, mi * 16 + lr, lg * 8);
#pragma unroll
    for (int ni = 0; ni < 4; ++ni)
      kb[ni] = *(const f16x8*)qk_at(kbase, ni * 16 + lr, lg * 8);
    f32x4 sc[4][4];
#pragma unroll
    for (int mi = 0; mi < 4; ++mi)
#pragma unroll
      for (int ni = 0; ni < 4; ++ni) {
        f32x4 z = {0.f, 0.f, 0.f, 0.f};
        sc[mi][ni] = __builtin_amdgcn_mfma_f32_16x16x32_f16(qa[mi], kb[ni], z, 0, 0, 0);
      }
    // softmax (row r = mi*16+lg*4+i lives in the 16 lanes of group lg)
#pragma unroll
    for (int mi = 0; mi < 4; ++mi)
#pragma unroll
      for (int i = 0; i < 4; ++i) {
        float m = fmaxf(fmaxf(sc[mi][0][i], sc[mi][1][i]),
                        fmaxf(sc[mi][2][i], sc[mi][3][i]));
        m = fmaxf(m, __shfl_xor(m, 1));
        m = fmaxf(m, __shfl_xor(m, 2));
        m = fmaxf(m, __shfl_xor(m, 4));
        m = fmaxf(m, __shfl_xor(m, 8));
        float s = 0.f;
#pragma unroll
        for (int ni = 0; ni < 4; ++ni) {
          float e = __expf(sc[mi][ni][i] - m);
          sc[mi][ni][i] = e;
          s += e;
        }
        s += __shfl_xor(s, 1);
        s += __shfl_xor(s, 2);
        s += __shfl_xor(s, 4);
        s += __shfl_xor(s, 8);
        oinv2[hl][mi][i] = 1.f / s;
      }
    // p (unnormalized) -> LDS, overlaying q+k
#pragma unroll
    for (int mi = 0; mi < 4; ++mi)
#pragma unroll
      for (int ni = 0; ni < 4; ++ni)
#pragma unroll
        for (int i = 0; i < 4; ++i)
          *p_at(scr, mi * 16 + lg * 4 + i, ni * 16 + lr) = (_Float16)sc[mi][ni][i];
    // PV: o = p(64x64) @ v(64x32), vT gives contiguous B-frags
#pragma unroll
    for (int mi = 0; mi < 4; ++mi)
#pragma unroll
      for (int nt2 = 0; nt2 < 2; ++nt2)
        oacc[hl][mi][nt2] = (f32x4){0.f, 0.f, 0.f, 0.f};
#pragma unroll
    for (int ks2 = 0; ks2 < 2; ++ks2) {
      f16x8 pa[4];
#pragma unroll
      for (int mi = 0; mi < 4; ++mi)
        pa[mi] = *(const f16x8*)p_at(scr, mi * 16 + lr, ks2 * 32 + lg * 8);
#pragma unroll
      for (int nt2 = 0; nt2 < 2; ++nt2) {
        f16x8 vb = *(const f16x8*)vt_at(vbase, nt2 * 16 + lr, ks2 * 32 + lg * 8);
#pragma unroll
        for (int mi = 0; mi < 4; ++mi)
          oacc[hl][mi][nt2] = __builtin_amdgcn_mfma_f32_16x16x32_f16(
              pa[mi], vb, oacc[hl][mi][nt2], 0, 0, 0);
      }
    }
#pragma unroll
    for (int mi = 0; mi < 4; ++mi)
#pragma unroll
      for (int nt2 = 0; nt2 < 2; ++nt2)
#pragma unroll
        for (int i = 0; i < 4; ++i)
          oacc[hl][mi][nt2][i] *= oinv2[hl][mi][i];
  }
  __syncthreads();  // all waves done reading xn

  // ---- phase 6: merged-head o -> LDS (overlays xn) ----
#pragma unroll
  for (int hl = 0; hl < 2; ++hl) {
    const int hcol = (2 * w + hl) * 32;
#pragma unroll
    for (int mi = 0; mi < 4; ++mi)
#pragma unroll
      for (int nt2 = 0; nt2 < 2; ++nt2)
#pragma unroll
        for (int i = 0; i < 4; ++i)
          *xn_at(smem, mi * 16 + lg * 4 + i, hcol + nt2 * 16 + lr) =
              (_Float16)oacc[hl][mi][nt2][i];
  }
  __syncthreads();

  // ---- phase 7: out projection + window reverse ----
  {
    f32x4 acc[4][4];
#pragma unroll
    for (int t = 0; t < 4; ++t)
#pragma unroll
      for (int mi = 0; mi < 4; ++mi) acc[t][mi] = (f32x4){0.f, 0.f, 0.f, 0.f};
#pragma unroll
    for (int kk = 0; kk < 8; ++kk) {
      f16x8 af[4];
#pragma unroll
      for (int mi = 0; mi < 4; ++mi)
        af[mi] = *(const f16x8*)xn_at(smem, mi * 16 + lr, kk * 32 + lg * 8);
#pragma unroll
      for (int ntl = 0; ntl < 4; ++ntl) {
        f16x8 bf = bfrag<USE_WS>(w16, wqkv32, wout32, 48 + w * 4 + ntl, kk, lane);
#pragma unroll
        for (int mi = 0; mi < 4; ++mi)
          acc[ntl][mi] = __builtin_amdgcn_mfma_f32_16x16x32_f16(af[mi], bf, acc[ntl][mi], 0, 0, 0);
      }
    }
#pragma unroll
    for (int ntl = 0; ntl < 4; ++ntl) {
      const int och = w * 64 + ntl * 16 + lr;
      const float bias = bout[och];
      float* ob = out + ((size_t)(b * C_ + och) * H_ + wh * 8) * W_ + ww * 8;
#pragma unroll
      for (int mi = 0; mi < 4; ++mi) {
        const int tb = mi * 16 + lg * 4;  // 4 consecutive tokens, same window row
        f32x4 ov;
#pragma unroll
        for (int i = 0; i < 4; ++i) ov[i] = acc[ntl][mi][i] + bias;
        *(f32x4*)&ob[(size_t)(tb >> 3) * W_ + (tb & 7)] = ov;
      }
    }
  }
}

extern "C" void kernel_launch(void* const* d_in, const int* in_sizes, int n_in,
                              void* d_out, int out_size, void* d_ws, size_t ws_size,
                              hipStream_t stream) {
  (void)in_sizes; (void)n_in; (void)out_size;
  const float* x     = (const float*)d_in[0];
  const float* gamma = (const float*)d_in[1];
  const float* beta  = (const float*)d_in[2];
  const float* wqkv  = (const float*)d_in[3];
  const float* bqkv  = (const float*)d_in[4];
  const float* wout  = (const float*)d_in[5];
  const float* bout  = (const float*)d_in[6];
  float* out = (float*)d_out;

  const size_t need_ws = (size_t)NFRAG * 8 * sizeof(_Float16);  // 512 KB
  const int shmem = 81920;

  if (ws_size >= need_ws) {
    _Float16* w16 = (_Float16*)d_ws;
    wcvt_kernel<<<NFRAG / 256, 256, 0, stream>>>(wqkv, wout, w16);
    static int attr_set = 0;
    if (!attr_set) {
      (void)hipFuncSetAttribute((const void*)winattn_kernel<true>,
                                hipFuncAttributeMaxDynamicSharedMemorySize, shmem);
      attr_set = 1;
    }
    winattn_kernel<true><<<NWIN, 256, shmem, stream>>>(
        x, gamma, beta, wqkv, bqkv, wout, bout, w16, out);
  } else {
    static int attr_set2 = 0;
    if (!attr_set2) {
      (void)hipFuncSetAttribute((const void*)winattn_kernel<false>,
                                hipFuncAttributeMaxDynamicSharedMemorySize, shmem);
      attr_set2 = 1;
    }
    winattn_kernel<false><<<NWIN, 256, shmem, stream>>>(
        x, gamma, beta, wqkv, bqkv, wout, bout, (const _Float16*)nullptr, out);
  }
}